// Round 1
// baseline (883.610 us; speedup 1.0000x reference)
//
#include <hip/hip_runtime.h>
#include <math.h>

typedef unsigned short u16;
typedef __bf16 bf16x8 __attribute__((ext_vector_type(8)));
typedef float  f32x4  __attribute__((ext_vector_type(4)));

__device__ __forceinline__ u16 f2bf(float f) {
    unsigned int u = __float_as_uint(f);
    u = (u + 0x7FFFu + ((u >> 16) & 1u)) >> 16;   // RNE
    return (u16)u;
}

// async global->LDS, 16B per lane; LDS dest must be lane-linear within the wave
__device__ __forceinline__ void gload16(const u16* g, u16* l) {
    __builtin_amdgcn_global_load_lds(
        (const __attribute__((address_space(1))) void*)g,
        (__attribute__((address_space(3))) void*)l, 16, 0, 0);
}

// ---------------------------------------------------------------------------
// fp32 -> bf16 elementwise convert (for the state input)
// ---------------------------------------------------------------------------
__global__ void cvt_bf16(const float* __restrict__ src, u16* __restrict__ dst, long n4) {
    long i = (long)blockIdx.x * blockDim.x + threadIdx.x;
    long stride = (long)gridDim.x * blockDim.x;
    for (; i < n4; i += stride) {
        float4 x = *(const float4*)(src + i * 4);
        ushort4 o;
        o.x = f2bf(x.x); o.y = f2bf(x.y); o.z = f2bf(x.z); o.w = f2bf(x.w);
        *(ushort4*)(dst + i * 4) = o;
    }
}

// ---------------------------------------------------------------------------
// Batched transpose + fp32->bf16 convert: src fp32 [G][K][N] -> dst bf16 [G][N][K]
// grid: (N/32, K/32, G), block 256
// ---------------------------------------------------------------------------
__global__ void transpose_k(const float* __restrict__ src, u16* __restrict__ dst,
                            int K, int N) {
    __shared__ u16 tile[32][33];
    long g = blockIdx.z;
    const float* s = src + g * (long)K * N;
    u16* d = dst + g * (long)K * N;
    int n0 = blockIdx.x * 32, k0 = blockIdx.y * 32;
    int tx = threadIdx.x & 31, ty = threadIdx.x >> 5;   // ty 0..7
#pragma unroll
    for (int r = ty; r < 32; r += 8)
        tile[r][tx] = f2bf(s[(long)(k0 + r) * N + n0 + tx]);
    __syncthreads();
#pragma unroll
    for (int r = ty; r < 32; r += 8)
        d[(long)(n0 + r) * K + k0 + tx] = tile[tx][r];
}

// ---------------------------------------------------------------------------
// Grouped GEMM: act(A[g] @ W[g]^T + b[g])  -> optional fp32 C and/or bf16 C
//   A:  bf16; element (g,m,i) at A + g*strideAn + m*lda + i
//   Wt: bf16 [G][N][K] (pre-transposed+converted)
//   Cf: fp32 out (nullable); Cb: bf16 out (nullable); each own stride/ld
// Tile: 128(M) x 128(N) x 32(K), 4 waves (2x2), 16x16x32 bf16 MFMA.
// Double-buffered LDS via global_load_lds(16B), ONE barrier per K-step:
//   iter kt: issue async stage of tile kt+1 -> ds_read/MFMA tile kt -> sync
// (__syncthreads drains vmcnt(0), making the staged tile visible.)
// act: 0=none 1=relu 2=tanh.  grid: ((N+127)/128, M/128, G), block 256
// ---------------------------------------------------------------------------
__global__ __launch_bounds__(256, 2)
void gemm_fnn(const u16* __restrict__ A, long strideAn, int lda,
              const u16* __restrict__ Wt, const float* __restrict__ bias,
              float* __restrict__ Cf, long sCfn, int ldcf,
              u16* __restrict__ Cb, long sCbn, int ldcb,
              int K, int N, int act)
{
    __shared__ __align__(16) u16 As[2][128 * 32];
    __shared__ __align__(16) u16 Bs[2][128 * 32];

    const int g  = blockIdx.z;
    const int m0 = blockIdx.y * 128;
    const int n0 = blockIdx.x * 128;

    const u16* Ag = A + (long)g * strideAn;
    const u16* Wg = Wt + (long)g * K * N;
    const float* bg = bias + (long)g * N;

    const int tid  = threadIdx.x;
    const int lane = tid & 63;
    const int wv   = tid >> 6;      // 0..3
    const int wm   = wv & 1;        // row half (M)
    const int wn   = wv >> 1;       // col half (N)
    const int lr   = lane & 15;
    const int lq   = lane >> 4;

    // staging map: thread tid handles row = tid>>2 (+64), k-chunk (tid&3)*8
    // LDS byte offset = tid*16 (+4096) -> lane-linear per wave (gload_lds ok)
    const int row0 = tid >> 2;            // 0..63
    const int c8   = (tid & 3) * 8;       // 0,8,16,24

    const u16* a_src = Ag + (long)(m0 + row0) * lda + c8;
    int nr0 = n0 + row0;      if (nr0 > N - 1) nr0 = N - 1;   // clamp (N=32 tail)
    int nr1 = n0 + row0 + 64; if (nr1 > N - 1) nr1 = N - 1;
    const u16* b_src0 = Wg + (long)nr0 * K + c8;
    const u16* b_src1 = Wg + (long)nr1 * K + c8;

    f32x4 acc[4][4] = {};
    const int KT = K >> 5;

    auto stage = [&](int buf, int k0) {
        u16* as = &As[buf][row0 * 32 + c8];     // = base + tid*16B
        u16* bs = &Bs[buf][row0 * 32 + c8];
        gload16(a_src + k0, as);
        gload16(a_src + 64 * (long)lda + k0, as + 64 * 32);
        gload16(b_src0 + k0, bs);
        gload16(b_src1 + k0, bs + 64 * 32);
    };

    stage(0, 0);
    __syncthreads();

    for (int kt = 0; kt < KT; ++kt) {
        const int cur = kt & 1;
        if (kt + 1 < KT) stage(cur ^ 1, (kt + 1) * 32);   // async, overlaps MFMAs

        bf16x8 af[4], bw[4];
#pragma unroll
        for (int i = 0; i < 4; ++i)
            af[i] = *(const bf16x8*)&As[cur][(wm * 64 + i * 16 + lr) * 32 + lq * 8];
#pragma unroll
        for (int j = 0; j < 4; ++j)
            bw[j] = *(const bf16x8*)&Bs[cur][(wn * 64 + j * 16 + lr) * 32 + lq * 8];
#pragma unroll
        for (int i = 0; i < 4; ++i)
#pragma unroll
            for (int j = 0; j < 4; ++j)
                acc[i][j] = __builtin_amdgcn_mfma_f32_16x16x32_bf16(
                    af[i], bw[j], acc[i][j], 0, 0, 0);

        __syncthreads();   // drains vmcnt(0)+lgkmcnt(0): next tile staged, reads done
    }

    // ---- epilogue: C/D layout col=lane&15, row=(lane>>4)*4+reg
#pragma unroll
    for (int j = 0; j < 4; ++j) {
        int n = n0 + wn * 64 + j * 16 + lr;
        if (n >= N) continue;
        float bvs = bg[n];
#pragma unroll
        for (int i = 0; i < 4; ++i) {
            int mb = m0 + wm * 64 + i * 16 + lq * 4;
#pragma unroll
            for (int r = 0; r < 4; ++r) {
                float v = acc[i][j][r] + bvs;
                if (act == 1) v = fmaxf(v, 0.f);
                else if (act == 2) v = tanhf(v);
                if (Cf) Cf[(long)g * sCfn + (long)(mb + r) * ldcf + n] = v;
                if (Cb) Cb[(long)g * sCbn + (long)(mb + r) * ldcb + n] = f2bf(v);
            }
        }
    }
}

// ---------------------------------------------------------------------------
extern "C" void kernel_launch(void* const* d_in, const int* in_sizes, int n_in,
                              void* d_out, int out_size, void* d_ws, size_t ws_size,
                              hipStream_t stream) {
    const int B = 4096, S = 256, D = 128, NA = 32, CD = 512;

    const float* state   = (const float*)d_in[0];
    const float* enc_w1  = (const float*)d_in[1];
    const float* enc_b1  = (const float*)d_in[2];
    const float* enc_wh  = (const float*)d_in[3];
    const float* enc_bh  = (const float*)d_in[4];
    const float* enc_wo  = (const float*)d_in[5];
    const float* enc_bo  = (const float*)d_in[6];
    const float *agg_w1[3], *agg_b1[3], *agg_wh[3], *agg_bh[3], *agg_wo[3], *agg_bo[3];
    for (int l = 0; l < 3; ++l) {
        agg_w1[l] = (const float*)d_in[7 + 6 * l + 0];
        agg_b1[l] = (const float*)d_in[7 + 6 * l + 1];
        agg_wh[l] = (const float*)d_in[7 + 6 * l + 2];
        agg_bh[l] = (const float*)d_in[7 + 6 * l + 3];
        agg_wo[l] = (const float*)d_in[7 + 6 * l + 4];
        agg_bo[l] = (const float*)d_in[7 + 6 * l + 5];
    }
    const float* head_w1 = (const float*)d_in[25];
    const float* head_b1 = (const float*)d_in[26];
    const float* head_wh = (const float*)d_in[27];
    const float* head_bh = (const float*)d_in[28];
    const float* head_wo = (const float*)d_in[29];
    const float* head_bo = (const float*)d_in[30];

    float* out    = (float*)d_out;               // embeds [B][85][128] fp32
    float* action = out + (long)B * 85 * D;      // [B][32] fp32

    // ---- carve workspace (bf16 elements)
    char* wsp = (char*)d_ws;
    auto carve = [&](long elems) {
        u16* p = (u16*)wsp;
        wsp += ((elems * 2 + 255) / 256) * 256;
        return p;
    };
    u16* enc_w1t = carve(64L * 128 * 256);
    u16* enc_wht = carve(64L * 128 * 128);
    u16* enc_wot = carve(64L * 128 * 128);
    u16 *agg_w1t[3], *agg_wht[3], *agg_wot[3];
    const int LN[3] = {16, 4, 1};
    for (int l = 0; l < 3; ++l) {
        agg_w1t[l] = carve((long)LN[l] * 512 * 512);
        agg_wht[l] = carve((long)LN[l] * 512 * 512);
        agg_wot[l] = carve((long)LN[l] * 128 * 512);
    }
    u16* head_w1t = carve(128L * 128);
    u16* head_wht = carve(128L * 128);
    u16* head_wot = carve(32L * 128);
    u16* stateB = carve((long)B * S);            // bf16 state
    u16* bufA   = carve(33554432L);              // rotating bf16 activations (64 MB)
    u16* bufB   = carve(33554432L);

    // ---- weight transposes+convert: fp32 [G][K][N] -> bf16 [G][N][K]
    auto T = [&](const float* src, u16* dst, int G, int K, int N) {
        dim3 gr(N / 32, K / 32, G);
        transpose_k<<<gr, 256, 0, stream>>>(src, dst, K, N);
    };
    T(enc_w1, enc_w1t, 64, 256, 128);
    T(enc_wh, enc_wht, 64, 128, 128);
    T(enc_wo, enc_wot, 64, 128, 128);
    for (int l = 0; l < 3; ++l) {
        T(agg_w1[l], agg_w1t[l], LN[l], 512, 512);
        T(agg_wh[l], agg_wht[l], LN[l], 512, 512);
        T(agg_wo[l], agg_wot[l], LN[l], 512, 128);
    }
    T(head_w1, head_w1t, 1, 128, 128);
    T(head_wh, head_wht, 1, 128, 128);
    T(head_wo, head_wot, 1, 128, 32);

    // state -> bf16 (once; replaces per-tile fp32 staging in the old kernel)
    cvt_bf16<<<1024, 256, 0, stream>>>(state, stateB, (long)B * S / 4);

    // ---- grouped GEMM launcher
    auto G = [&](const u16* Ap, long sAn, int lda,
                 const u16* Wt, const float* bias,
                 float* Cf, long sCfn, int ldcf,
                 u16* Cb, long sCbn, int ldcb,
                 int K, int N, int act, int groups) {
        dim3 gr((N + 127) / 128, B / 128, groups);
        gemm_fnn<<<gr, 256, 0, stream>>>(Ap, sAn, lda, Wt, bias,
                                         Cf, sCfn, ldcf, Cb, sCbn, ldcb, K, N, act);
    };
    const int LD = 85 * D;   // 10880

    // encoders (A = stateB shared across 64 groups)
    G(stateB, 0, S, enc_w1t, enc_b1, nullptr, 0, 0, bufA, (long)B * D, D, S, D, 1, 64);
    G(bufA, (long)B * D, D, enc_wht, enc_bh, nullptr, 0, 0, bufB, (long)B * D, D, D, D, 1, 64);
    // enc out: fp32 -> out[:, 0:64, :]  +  bf16 mirror bufA laid out [B][64*D]
    G(bufB, (long)B * D, D, enc_wot, enc_bo, out, D, LD, bufA, D, 64 * D, D, D, 0, 64);

    // agg level 0: A = mirror [B][64*D]; (g,m,i) -> m*8192 + g*512 + i
    G(bufA, 4L * D, 64 * D, agg_w1t[0], agg_b1[0], nullptr, 0, 0,
      bufB, (long)B * CD, CD, CD, CD, 1, 16);
    G(bufB, (long)B * CD, CD, agg_wht[0], agg_bh[0], nullptr, 0, 0,
      bufA, (long)B * CD, CD, CD, CD, 1, 16);
    G(bufA, (long)B * CD, CD, agg_wot[0], agg_bo[0],
      out + 64L * D, D, LD, bufB, D, 16 * D, CD, D, 0, 16);

    // agg level 1: A = mirror [B][16*D]
    G(bufB, 4L * D, 16 * D, agg_w1t[1], agg_b1[1], nullptr, 0, 0,
      bufA, (long)B * CD, CD, CD, CD, 1, 4);
    G(bufA, (long)B * CD, CD, agg_wht[1], agg_bh[1], nullptr, 0, 0,
      bufB, (long)B * CD, CD, CD, CD, 1, 4);
    G(bufB, (long)B * CD, CD, agg_wot[1], agg_bo[1],
      out + 80L * D, D, LD, bufA, D, 4 * D, CD, D, 0, 4);

    // agg level 2 (root): A = mirror [B][4*D]
    G(bufA, 0, 4 * D, agg_w1t[2], agg_b1[2], nullptr, 0, 0, bufB, 0, CD, CD, CD, 1, 1);
    G(bufB, 0, CD, agg_wht[2], agg_bh[2], nullptr, 0, 0, bufA, 0, CD, CD, CD, 1, 1);
    G(bufA, 0, CD, agg_wot[2], agg_bo[2],
      out + 84L * D, D, LD, bufB, 0, D, CD, D, 0, 1);

    // head: A = root mirror [B][D]
    G(bufB, 0, D, head_w1t, head_b1, nullptr, 0, 0, bufA, 0, D, D, D, 1, 1);
    G(bufA, 0, D, head_wht, head_bh, nullptr, 0, 0, bufB, 0, D, D, D, 1, 1);
    G(bufB, 0, D, head_wot, head_bo, action, 0, NA, nullptr, 0, 0, D, NA, 2, 1);
}

// Round 2
// 702.044 us; speedup vs baseline: 1.2586x; 1.2586x over previous
//
#include <hip/hip_runtime.h>
#include <math.h>

typedef unsigned short u16;
typedef __bf16 bf16x8 __attribute__((ext_vector_type(8)));
typedef float  f32x4  __attribute__((ext_vector_type(4)));

__device__ __forceinline__ u16 f2bf(float f) {
    unsigned int u = __float_as_uint(f);
    u = (u + 0x7FFFu + ((u >> 16) & 1u)) >> 16;   // RNE
    return (u16)u;
}

// async global->LDS, 16B/lane; LDS dest must be lane-linear within each wave
__device__ __forceinline__ void gload16(const u16* g, u16* l) {
    __builtin_amdgcn_global_load_lds(
        (const __attribute__((address_space(1))) void*)g,
        (__attribute__((address_space(3))) void*)l, 16, 0, 0);
}

// ---------------------------------------------------------------------------
// Merged weight transpose+convert (mode 0: fp32 [G][K][N] -> bf16 [G][N][K])
// and linear fp32->bf16 convert (mode 1, 1024 elems/tile). One launch.
// ---------------------------------------------------------------------------
struct TJob { const float* src; u16* dst; int K, N, tpg, gbase, mode; };
struct TTab { TJob j[16]; };

__global__ void transpose_multi(TTab tab, int njobs) {
    __shared__ u16 tile[32][33];
    int bid = blockIdx.x;
    int ji = 0;
#pragma unroll 1
    for (int t = 1; t < njobs; ++t)
        if (bid >= tab.j[t].gbase) ji = t;
    TJob jb = tab.j[ji];
    int t = bid - jb.gbase;
    if (jb.mode == 1) {                       // linear convert
        long off = (long)t * 1024 + threadIdx.x * 4;
        float4 x = *(const float4*)(jb.src + off);
        ushort4 o;
        o.x = f2bf(x.x); o.y = f2bf(x.y); o.z = f2bf(x.z); o.w = f2bf(x.w);
        *(ushort4*)(jb.dst + off) = o;
        return;
    }
    int g = t / jb.tpg, r = t % jb.tpg;
    int nt = jb.N >> 5;
    int k0 = (r / nt) * 32, n0 = (r % nt) * 32;
    const float* s = jb.src + (long)g * jb.K * jb.N;
    u16* d = jb.dst + (long)g * jb.K * jb.N;
    int tx = threadIdx.x & 31, ty = threadIdx.x >> 5;
#pragma unroll
    for (int rr = ty; rr < 32; rr += 8)
        tile[rr][tx] = f2bf(s[(long)(k0 + rr) * jb.N + n0 + tx]);
    __syncthreads();
#pragma unroll
    for (int rr = ty; rr < 32; rr += 8)
        d[(long)(n0 + rr) * jb.K + k0 + tx] = tile[tx][rr];
}

// ---------------------------------------------------------------------------
// Fused 3-layer FNN chain, hidden width 128 (encoders, head).
// Block = 128 rows x 128 cols, 4 waves (2Mx2N). h kept in LDS (ld=152: 2-way
// banks = free). Layers: L1 relu(X@W1+b1) -> h; L2 relu(h@Wh+bh) -> h;
// L3 act3(h@Wo+bo) -> Cf (+ optional bf16 mirror Cb).
// Wt layouts: W1t [G][128][K1], Wht [G][128][128], Wot [G][Do][128].
// grid: (M/128, G), block 256
// ---------------------------------------------------------------------------
__global__ __launch_bounds__(256, 2)
void fnn_chain128(const u16* __restrict__ X, long sXg, int ldx, int K1,
                  const u16* __restrict__ W1t, const float* __restrict__ b1,
                  const u16* __restrict__ Wht, const float* __restrict__ bh,
                  const u16* __restrict__ Wot, const float* __restrict__ bo,
                  int Do, int act3,
                  float* __restrict__ Cf, long sCfg, int ldcf,
                  u16* __restrict__ Cb, long sCbg, int ldcb)
{
    __shared__ __align__(16) u16 As[2][128 * 32];
    __shared__ __align__(16) u16 Bs[2][128 * 32];
    __shared__ __align__(16) u16 h[128 * 152];

    const int g   = blockIdx.y;
    const int m0  = blockIdx.x * 128;
    const int tid = threadIdx.x;
    const int lane = tid & 63, wv = tid >> 6;
    const int wm = wv & 1, wn = wv >> 1;
    const int lr = lane & 15, lq = lane >> 4;
    const int row0 = tid >> 2, c8 = (tid & 3) * 8;

    const u16* a_src = X + (long)g * sXg + (long)(m0 + row0) * ldx + c8;
    const u16* w1r   = W1t + (long)g * 128 * K1 + (long)row0 * K1 + c8;
    const u16* whr   = Wht + (long)g * 128 * 128 + (long)row0 * 128 + c8;

    const f32x4 z4 = {0.f, 0.f, 0.f, 0.f};
    f32x4 acc[4][4];
#pragma unroll
    for (int i = 0; i < 4; ++i)
#pragma unroll
        for (int j = 0; j < 4; ++j) acc[i][j] = z4;

    // ---------------- L1: X @ W1
    const int KT1 = K1 >> 5;
    auto stage1 = [&](int buf, int k0) {
        gload16(a_src + k0,                  &As[buf][row0 * 32 + c8]);
        gload16(a_src + (long)64 * ldx + k0, &As[buf][(row0 + 64) * 32 + c8]);
        gload16(w1r + k0,                    &Bs[buf][row0 * 32 + c8]);
        gload16(w1r + (long)64 * K1 + k0,    &Bs[buf][(row0 + 64) * 32 + c8]);
    };
    stage1(0, 0);
    __syncthreads();
    for (int kt = 0; kt < KT1; ++kt) {
        int cur = kt & 1;
        if (kt + 1 < KT1) stage1(cur ^ 1, (kt + 1) * 32);
        bf16x8 af[4], bw[4];
#pragma unroll
        for (int i = 0; i < 4; ++i)
            af[i] = *(const bf16x8*)&As[cur][(wm * 64 + i * 16 + lr) * 32 + lq * 8];
#pragma unroll
        for (int j = 0; j < 4; ++j)
            bw[j] = *(const bf16x8*)&Bs[cur][(wn * 64 + j * 16 + lr) * 32 + lq * 8];
#pragma unroll
        for (int i = 0; i < 4; ++i)
#pragma unroll
            for (int j = 0; j < 4; ++j)
                acc[i][j] = __builtin_amdgcn_mfma_f32_16x16x32_bf16(
                    af[i], bw[j], acc[i][j], 0, 0, 0);
        __syncthreads();
    }
    {   // bias + relu -> h
        const float* bg = b1 + (long)g * 128;
#pragma unroll
        for (int j = 0; j < 4; ++j) {
            int n = wn * 64 + j * 16 + lr;
            float bb = bg[n];
#pragma unroll
            for (int i = 0; i < 4; ++i) {
                int mb = wm * 64 + i * 16 + lq * 4;
#pragma unroll
                for (int r = 0; r < 4; ++r)
                    h[(mb + r) * 152 + n] = f2bf(fmaxf(acc[i][j][r] + bb, 0.f));
            }
        }
    }

    // ---------------- L2: h @ Wh
#pragma unroll
    for (int i = 0; i < 4; ++i)
#pragma unroll
        for (int j = 0; j < 4; ++j) acc[i][j] = z4;
    auto stage2 = [&](int buf, int k0) {
        gload16(whr + k0,                  &Bs[buf][row0 * 32 + c8]);
        gload16(whr + (long)64 * 128 + k0, &Bs[buf][(row0 + 64) * 32 + c8]);
    };
    stage2(0, 0);
    __syncthreads();
    for (int kt = 0; kt < 4; ++kt) {
        int cur = kt & 1;
        if (kt + 1 < 4) stage2(cur ^ 1, (kt + 1) * 32);
        bf16x8 af[4], bw[4];
#pragma unroll
        for (int i = 0; i < 4; ++i)
            af[i] = *(const bf16x8*)&h[(wm * 64 + i * 16 + lr) * 152 + kt * 32 + lq * 8];
#pragma unroll
        for (int j = 0; j < 4; ++j)
            bw[j] = *(const bf16x8*)&Bs[cur][(wn * 64 + j * 16 + lr) * 32 + lq * 8];
#pragma unroll
        for (int i = 0; i < 4; ++i)
#pragma unroll
            for (int j = 0; j < 4; ++j)
                acc[i][j] = __builtin_amdgcn_mfma_f32_16x16x32_bf16(
                    af[i], bw[j], acc[i][j], 0, 0, 0);
        __syncthreads();
    }
    {   // bias + relu -> h (in place; all reads drained by final barrier)
        const float* bg = bh + (long)g * 128;
#pragma unroll
        for (int j = 0; j < 4; ++j) {
            int n = wn * 64 + j * 16 + lr;
            float bb = bg[n];
#pragma unroll
            for (int i = 0; i < 4; ++i) {
                int mb = wm * 64 + i * 16 + lq * 4;
#pragma unroll
                for (int r = 0; r < 4; ++r)
                    h[(mb + r) * 152 + n] = f2bf(fmaxf(acc[i][j][r] + bb, 0.f));
            }
        }
    }

    // ---------------- L3: h @ Wo
#pragma unroll
    for (int i = 0; i < 4; ++i)
#pragma unroll
        for (int j = 0; j < 4; ++j) acc[i][j] = z4;
    const int nr0 = (row0 < Do) ? row0 : Do - 1;          // clamp (Do=32 tail)
    const int nr1 = (row0 + 64 < Do) ? row0 + 64 : Do - 1;
    const u16* wor0 = Wot + (long)g * Do * 128 + (long)nr0 * 128 + c8;
    const u16* wor1 = Wot + (long)g * Do * 128 + (long)nr1 * 128 + c8;
    auto stage3 = [&](int buf, int k0) {
        gload16(wor0 + k0, &Bs[buf][row0 * 32 + c8]);
        gload16(wor1 + k0, &Bs[buf][(row0 + 64) * 32 + c8]);
    };
    stage3(0, 0);
    __syncthreads();
    for (int kt = 0; kt < 4; ++kt) {
        int cur = kt & 1;
        if (kt + 1 < 4) stage3(cur ^ 1, (kt + 1) * 32);
        bf16x8 af[4], bw[4];
#pragma unroll
        for (int i = 0; i < 4; ++i)
            af[i] = *(const bf16x8*)&h[(wm * 64 + i * 16 + lr) * 152 + kt * 32 + lq * 8];
#pragma unroll
        for (int j = 0; j < 4; ++j)
            bw[j] = *(const bf16x8*)&Bs[cur][(wn * 64 + j * 16 + lr) * 32 + lq * 8];
#pragma unroll
        for (int i = 0; i < 4; ++i)
#pragma unroll
            for (int j = 0; j < 4; ++j)
                acc[i][j] = __builtin_amdgcn_mfma_f32_16x16x32_bf16(
                    af[i], bw[j], acc[i][j], 0, 0, 0);
        __syncthreads();
    }
    {   // bias + act3 -> Cf (+Cb mirror)
        const float* bg = bo + (long)g * Do;
#pragma unroll
        for (int j = 0; j < 4; ++j) {
            int n = wn * 64 + j * 16 + lr;
            if (n >= Do) continue;
            float bb = bg[n];
#pragma unroll
            for (int i = 0; i < 4; ++i) {
                int mb = wm * 64 + i * 16 + lq * 4;
#pragma unroll
                for (int r = 0; r < 4; ++r) {
                    float v = acc[i][j][r] + bb;
                    if (act3 == 2) v = tanhf(v);
                    long mrow = m0 + mb + r;
                    Cf[(long)g * sCfg + mrow * ldcf + n] = v;
                    if (Cb) Cb[(long)g * sCbg + mrow * ldcb + n] = f2bf(v);
                }
            }
        }
    }
}

// ---------------------------------------------------------------------------
// Fused 3-layer FNN chain, hidden width 512 (aggregators). K=512 all layers.
// Block = 64 rows x 512 cols, 8 waves (1Mx8N for L1/L2; 2Mx4N of 32x32 for
// L3 with Do=128). h[64][536] in LDS. LDS total ~139KB -> 1 block/CU.
// W1t/Wht [G][512][512], Wot [G][128][512].
// grid: (M/64, G), block 512
// ---------------------------------------------------------------------------
__global__ __launch_bounds__(512, 2)
void fnn_chain512(const u16* __restrict__ X, long sXg, int ldx,
                  const u16* __restrict__ W1t, const float* __restrict__ b1,
                  const u16* __restrict__ Wht, const float* __restrict__ bh,
                  const u16* __restrict__ Wot, const float* __restrict__ bo,
                  float* __restrict__ Cf, long sCfg, int ldcf,
                  u16* __restrict__ Cb, long sCbg, int ldcb)
{
    __shared__ __align__(16) u16 As[2][64 * 32];
    __shared__ __align__(16) u16 Bs[2][512 * 32];
    __shared__ __align__(16) u16 h[64 * 536];

    const int g   = blockIdx.y;
    const int m0  = blockIdx.x * 64;
    const int tid = threadIdx.x;
    const int lane = tid & 63, wv = tid >> 6;     // wv 0..7
    const int lr = lane & 15, lq = lane >> 4;
    const int row0 = tid >> 2, c8 = (tid & 3) * 8;  // row0 0..127

    const u16* a_src = X + (long)g * sXg + (long)(m0 + row0) * ldx + c8; // used tid<256
    const u16* w1r = W1t + (long)g * 512 * 512 + (long)row0 * 512 + c8;
    const u16* whr = Wht + (long)g * 512 * 512 + (long)row0 * 512 + c8;
    const u16* wor = Wot + (long)g * 128 * 512 + (long)row0 * 512 + c8;

    const f32x4 z4 = {0.f, 0.f, 0.f, 0.f};
    f32x4 acc[4][4];
#pragma unroll
    for (int i = 0; i < 4; ++i)
#pragma unroll
        for (int j = 0; j < 4; ++j) acc[i][j] = z4;

    // ---------------- L1: X @ W1  (K=512, 16 steps)
    auto stage1 = [&](int buf, int k0) {
        if (tid < 256) gload16(a_src + k0, &As[buf][row0 * 32 + c8]);
#pragma unroll
        for (int r = 0; r < 4; ++r)
            gload16(w1r + (long)(128 * r) * 512 + k0,
                    &Bs[buf][(row0 + 128 * r) * 32 + c8]);
    };
    stage1(0, 0);
    __syncthreads();
    for (int kt = 0; kt < 16; ++kt) {
        int cur = kt & 1;
        if (kt + 1 < 16) stage1(cur ^ 1, (kt + 1) * 32);
        bf16x8 af[4], bw[4];
#pragma unroll
        for (int i = 0; i < 4; ++i)
            af[i] = *(const bf16x8*)&As[cur][(i * 16 + lr) * 32 + lq * 8];
#pragma unroll
        for (int j = 0; j < 4; ++j)
            bw[j] = *(const bf16x8*)&Bs[cur][(wv * 64 + j * 16 + lr) * 32 + lq * 8];
#pragma unroll
        for (int i = 0; i < 4; ++i)
#pragma unroll
            for (int j = 0; j < 4; ++j)
                acc[i][j] = __builtin_amdgcn_mfma_f32_16x16x32_bf16(
                    af[i], bw[j], acc[i][j], 0, 0, 0);
        __syncthreads();
    }
    {   // b1 + relu -> h
        const float* bg = b1 + (long)g * 512;
#pragma unroll
        for (int j = 0; j < 4; ++j) {
            int n = wv * 64 + j * 16 + lr;
            float bb = bg[n];
#pragma unroll
            for (int i = 0; i < 4; ++i) {
                int mb = i * 16 + lq * 4;
#pragma unroll
                for (int r = 0; r < 4; ++r)
                    h[(mb + r) * 536 + n] = f2bf(fmaxf(acc[i][j][r] + bb, 0.f));
            }
        }
    }

    // ---------------- L2: h @ Wh (K=512)
#pragma unroll
    for (int i = 0; i < 4; ++i)
#pragma unroll
        for (int j = 0; j < 4; ++j) acc[i][j] = z4;
    auto stage2 = [&](int buf, int k0) {
#pragma unroll
        for (int r = 0; r < 4; ++r)
            gload16(whr + (long)(128 * r) * 512 + k0,
                    &Bs[buf][(row0 + 128 * r) * 32 + c8]);
    };
    stage2(0, 0);
    __syncthreads();
    for (int kt = 0; kt < 16; ++kt) {
        int cur = kt & 1;
        if (kt + 1 < 16) stage2(cur ^ 1, (kt + 1) * 32);
        bf16x8 af[4], bw[4];
#pragma unroll
        for (int i = 0; i < 4; ++i)
            af[i] = *(const bf16x8*)&h[(i * 16 + lr) * 536 + kt * 32 + lq * 8];
#pragma unroll
        for (int j = 0; j < 4; ++j)
            bw[j] = *(const bf16x8*)&Bs[cur][(wv * 64 + j * 16 + lr) * 32 + lq * 8];
#pragma unroll
        for (int i = 0; i < 4; ++i)
#pragma unroll
            for (int j = 0; j < 4; ++j)
                acc[i][j] = __builtin_amdgcn_mfma_f32_16x16x32_bf16(
                    af[i], bw[j], acc[i][j], 0, 0, 0);
        __syncthreads();
    }
    {   // bh + relu -> h (in place)
        const float* bg = bh + (long)g * 512;
#pragma unroll
        for (int j = 0; j < 4; ++j) {
            int n = wv * 64 + j * 16 + lr;
            float bb = bg[n];
#pragma unroll
            for (int i = 0; i < 4; ++i) {
                int mb = i * 16 + lq * 4;
#pragma unroll
                for (int r = 0; r < 4; ++r)
                    h[(mb + r) * 536 + n] = f2bf(fmaxf(acc[i][j][r] + bb, 0.f));
            }
        }
    }

    // ---------------- L3: h @ Wo (K=512, Do=128); 8 waves = 2Mx4N of 32x32
    const int wm3 = wv & 1, wn3 = wv >> 1;   // wn3 0..3
    f32x4 a2[2][2];
#pragma unroll
    for (int i = 0; i < 2; ++i)
#pragma unroll
        for (int j = 0; j < 2; ++j) a2[i][j] = z4;
    auto stage3 = [&](int buf, int k0) {
        gload16(wor + k0, &Bs[buf][row0 * 32 + c8]);   // 128 rows, one granule
    };
    stage3(0, 0);
    __syncthreads();
    for (int kt = 0; kt < 16; ++kt) {
        int cur = kt & 1;
        if (kt + 1 < 16) stage3(cur ^ 1, (kt + 1) * 32);
        bf16x8 af2[2], bw2[2];
#pragma unroll
        for (int i = 0; i < 2; ++i)
            af2[i] = *(const bf16x8*)&h[(wm3 * 32 + i * 16 + lr) * 536 + kt * 32 + lq * 8];
#pragma unroll
        for (int j = 0; j < 2; ++j)
            bw2[j] = *(const bf16x8*)&Bs[cur][(wn3 * 32 + j * 16 + lr) * 32 + lq * 8];
#pragma unroll
        for (int i = 0; i < 2; ++i)
#pragma unroll
            for (int j = 0; j < 2; ++j)
                a2[i][j] = __builtin_amdgcn_mfma_f32_16x16x32_bf16(
                    af2[i], bw2[j], a2[i][j], 0, 0, 0);
        __syncthreads();
    }
    {   // bo -> Cf (+Cb mirror), no activation
        const float* bg = bo + (long)g * 128;
#pragma unroll
        for (int j = 0; j < 2; ++j) {
            int n = wn3 * 32 + j * 16 + lr;
            float bb = bg[n];
#pragma unroll
            for (int i = 0; i < 2; ++i) {
                int mb = wm3 * 32 + i * 16 + lq * 4;
#pragma unroll
                for (int r = 0; r < 4; ++r) {
                    float v = a2[i][j][r] + bb;
                    long mrow = m0 + mb + r;
                    Cf[(long)g * sCfg + mrow * ldcf + n] = v;
                    if (Cb) Cb[(long)g * sCbg + mrow * ldcb + n] = f2bf(v);
                }
            }
        }
    }
}

// ---------------------------------------------------------------------------
extern "C" void kernel_launch(void* const* d_in, const int* in_sizes, int n_in,
                              void* d_out, int out_size, void* d_ws, size_t ws_size,
                              hipStream_t stream) {
    const int B = 4096, S = 256, D = 128, NA = 32, CD = 512;

    const float* state   = (const float*)d_in[0];
    const float* enc_w1  = (const float*)d_in[1];
    const float* enc_b1  = (const float*)d_in[2];
    const float* enc_wh  = (const float*)d_in[3];
    const float* enc_bh  = (const float*)d_in[4];
    const float* enc_wo  = (const float*)d_in[5];
    const float* enc_bo  = (const float*)d_in[6];
    const float *agg_w1[3], *agg_b1[3], *agg_wh[3], *agg_bh[3], *agg_wo[3], *agg_bo[3];
    for (int l = 0; l < 3; ++l) {
        agg_w1[l] = (const float*)d_in[7 + 6 * l + 0];
        agg_b1[l] = (const float*)d_in[7 + 6 * l + 1];
        agg_wh[l] = (const float*)d_in[7 + 6 * l + 2];
        agg_bh[l] = (const float*)d_in[7 + 6 * l + 3];
        agg_wo[l] = (const float*)d_in[7 + 6 * l + 4];
        agg_bo[l] = (const float*)d_in[7 + 6 * l + 5];
    }
    const float* head_w1 = (const float*)d_in[25];
    const float* head_b1 = (const float*)d_in[26];
    const float* head_wh = (const float*)d_in[27];
    const float* head_bh = (const float*)d_in[28];
    const float* head_wo = (const float*)d_in[29];
    const float* head_bo = (const float*)d_in[30];

    float* out    = (float*)d_out;               // embeds [B][85][128] fp32
    float* action = out + (long)B * 85 * D;      // [B][32] fp32

    // ---- carve workspace (bf16 elements)
    char* wsp = (char*)d_ws;
    auto carve = [&](long elems) {
        u16* p = (u16*)wsp;
        wsp += ((elems * 2 + 255) / 256) * 256;
        return p;
    };
    u16* enc_w1t = carve(64L * 128 * 256);
    u16* enc_wht = carve(64L * 128 * 128);
    u16* enc_wot = carve(64L * 128 * 128);
    u16 *agg_w1t[3], *agg_wht[3], *agg_wot[3];
    const int LN[3] = {16, 4, 1};
    for (int l = 0; l < 3; ++l) {
        agg_w1t[l] = carve((long)LN[l] * 512 * 512);
        agg_wht[l] = carve((long)LN[l] * 512 * 512);
        agg_wot[l] = carve((long)LN[l] * 128 * 512);
    }
    u16* head_w1t = carve(128L * 128);
    u16* head_wht = carve(128L * 128);
    u16* head_wot = carve(32L * 128);
    u16* stateB = carve((long)B * S);            // bf16 state
    u16* bufA   = carve(33554432L);              // bf16 activation mirrors
    u16* bufB   = carve(33554432L);

    // ---- build merged transpose/convert table (one launch)
    TTab tab = {};
    int nj = 0, base = 0;
    auto addT = [&](const float* s, u16* d, int G, int K, int N) {
        int tpg = (K / 32) * (N / 32);
        tab.j[nj] = {s, d, K, N, tpg, base, 0};
        base += G * tpg; ++nj;
    };
    auto addC = [&](const float* s, u16* d, long elems) {
        tab.j[nj] = {s, d, 0, 0, 0, base, 1};
        base += (int)(elems / 1024); ++nj;
    };
    addT(enc_w1, enc_w1t, 64, 256, 128);
    addT(enc_wh, enc_wht, 64, 128, 128);
    addT(enc_wo, enc_wot, 64, 128, 128);
    for (int l = 0; l < 3; ++l) {
        addT(agg_w1[l], agg_w1t[l], LN[l], 512, 512);
        addT(agg_wh[l], agg_wht[l], LN[l], 512, 512);
        addT(agg_wo[l], agg_wot[l], LN[l], 512, 128);
    }
    addT(head_w1, head_w1t, 1, 128, 128);
    addT(head_wh, head_wht, 1, 128, 128);
    addT(head_wo, head_wot, 1, 128, 32);
    addC(state, stateB, (long)B * S);
    transpose_multi<<<base, 256, 0, stream>>>(tab, nj);

    const int LD = 85 * D;   // 10880

    // encoders: fused chain, out fp32 embeds[:,0:64,:] + bf16 mirror [B][64D]
    fnn_chain128<<<dim3(32, 64), 256, 0, stream>>>(
        stateB, 0, S, 256,
        enc_w1t, enc_b1, enc_wht, enc_bh, enc_wot, enc_bo, 128, 0,
        out, D, LD, bufA, D, 64 * D);

    // agg level 0: X = enc mirror [B][64D]; out t=64.. + mirror [B][16D]
    fnn_chain512<<<dim3(64, 16), 512, 0, stream>>>(
        bufA, 512, 64 * D,
        agg_w1t[0], agg_b1[0], agg_wht[0], agg_bh[0], agg_wot[0], agg_bo[0],
        out + 64L * D, D, LD, bufB, D, 16 * D);

    // agg level 1: X = [B][16D]; out t=80.. + mirror [B][4D]
    fnn_chain512<<<dim3(64, 4), 512, 0, stream>>>(
        bufB, 512, 16 * D,
        agg_w1t[1], agg_b1[1], agg_wht[1], agg_bh[1], agg_wot[1], agg_bo[1],
        out + 80L * D, D, LD, bufA, D, 4 * D);

    // agg level 2 (root): X = [B][4D]; out t=84 + mirror [B][D]
    fnn_chain512<<<dim3(64, 1), 512, 0, stream>>>(
        bufA, 0, 4 * D,
        agg_w1t[2], agg_b1[2], agg_wht[2], agg_bh[2], agg_wot[2], agg_bo[2],
        out + 84L * D, D, LD, bufB, 0, D);

    // head: fused chain, X = root mirror [B][D], tanh, Do=32
    fnn_chain128<<<dim3(32, 1), 256, 0, stream>>>(
        bufB, 0, D, 128,
        head_w1t, head_b1, head_wht, head_bh, head_wot, head_bo, 32, 2,
        action, 0, NA, nullptr, 0, 0);
}